// Round 1
// baseline (7168.015 us; speedup 1.0000x reference)
//
#include <hip/hip_runtime.h>
#include <math.h>

#define BB 4
#define SS 1000
#define DD 512
#define HH 8
#define HD 64
#define LL 4
#define FFD 2048
#define VV 32000
#define MM (BB*SS)   // 4000

// ---------------------------------------------------------------------------
// Embedding + positional encoding: x[b,s,d] = emb[tok[b,s],d] + pe[s,d]
// ---------------------------------------------------------------------------
__global__ __launch_bounds__(256) void embed_pe_kernel(
    const int* __restrict__ tokens, const float* __restrict__ emb,
    float* __restrict__ x)
{
    int idx = blockIdx.x * 256 + threadIdx.x;      // < B*S*D = 2,048,000
    int d  = idx & (DD - 1);
    int bs = idx >> 9;
    int s  = bs % SS;
    int tok = tokens[bs];
    float i2 = (float)(d & ~1);                    // 2*(d/2)
    float dv = expf(i2 * (-9.210340371976184f / (float)DD)); // -ln(10000)/D
    float ang = (float)s * dv;
    float pe = (d & 1) ? cosf(ang) : sinf(ang);
    x[idx] = emb[(size_t)tok * DD + d] + pe;
}

// ---------------------------------------------------------------------------
// Generic fp32 GEMM: C[M,N] = A[M,K] @ W[K,N] + bias[N], optional ReLU.
// BM=128, BN=64, BK=16, 256 threads, 8x4 micro-tile per thread.
// Requires: K % 16 == 0, N % 64 == 0. M guarded.
// ---------------------------------------------------------------------------
__global__ __launch_bounds__(256) void gemm_bias_kernel(
    const float* __restrict__ A, const float* __restrict__ W,
    const float* __restrict__ bias, float* __restrict__ C,
    int M, int N, int K, int relu)
{
    __shared__ float As[16][128];   // [k][m] (transposed tile)
    __shared__ float Bs[16][64];    // [k][n]
    const int tid = threadIdx.x;
    const int bm = blockIdx.y * 128;
    const int bn = blockIdx.x * 64;
    const int tx = tid & 15;        // N dir: 16 x 4 = 64
    const int ty = tid >> 4;        // M dir: 16 x 8 = 128

    float acc[8][4];
#pragma unroll
    for (int i = 0; i < 8; i++)
#pragma unroll
        for (int j = 0; j < 4; j++) acc[i][j] = 0.f;

    for (int k0 = 0; k0 < K; k0 += 16) {
        // A tile: 128 rows x 16 k. 2048 elems, 8 per thread (2 x float4).
#pragma unroll
        for (int p = 0; p < 2; p++) {
            int flat = p * 1024 + tid * 4;
            int m = flat >> 4;
            int ks = flat & 15;
            int gm = bm + m;
            float4 av = make_float4(0.f, 0.f, 0.f, 0.f);
            if (gm < M) av = *(const float4*)&A[(size_t)gm * K + k0 + ks];
            As[ks + 0][m] = av.x;
            As[ks + 1][m] = av.y;
            As[ks + 2][m] = av.z;
            As[ks + 3][m] = av.w;
        }
        // W tile: 16 k x 64 n. 1024 elems, 4 per thread.
        {
            int k = tid >> 4;
            int ns = (tid & 15) * 4;
            *(float4*)&Bs[k][ns] = *(const float4*)&W[(size_t)(k0 + k) * N + bn + ns];
        }
        __syncthreads();
#pragma unroll
        for (int k = 0; k < 16; k++) {
            float4 a0 = *(const float4*)&As[k][ty * 8];
            float4 a1 = *(const float4*)&As[k][ty * 8 + 4];
            float4 b0 = *(const float4*)&Bs[k][tx * 4];
            float a[8] = {a0.x, a0.y, a0.z, a0.w, a1.x, a1.y, a1.z, a1.w};
            float b[4] = {b0.x, b0.y, b0.z, b0.w};
#pragma unroll
            for (int i = 0; i < 8; i++)
#pragma unroll
                for (int j = 0; j < 4; j++)
                    acc[i][j] = fmaf(a[i], b[j], acc[i][j]);
        }
        __syncthreads();
    }

    float4 bv = *(const float4*)&bias[bn + tx * 4];
#pragma unroll
    for (int i = 0; i < 8; i++) {
        int gm = bm + ty * 8 + i;
        if (gm < M) {
            float4 c;
            c.x = acc[i][0] + bv.x;
            c.y = acc[i][1] + bv.y;
            c.z = acc[i][2] + bv.z;
            c.w = acc[i][3] + bv.w;
            if (relu) {
                c.x = fmaxf(c.x, 0.f); c.y = fmaxf(c.y, 0.f);
                c.z = fmaxf(c.z, 0.f); c.w = fmaxf(c.w, 0.f);
            }
            *(float4*)&C[(size_t)gm * N + bn + tx * 4] = c;
        }
    }
}

// ---------------------------------------------------------------------------
// Attention: one block per (b, h, q-tile of 8 rows). grid = B*H*(S/8) = 4000.
// q/k/v are [B*S, D] with head h at columns [h*64, h*64+64).
// ---------------------------------------------------------------------------
#define SC_PITCH 1028   // 8-row score pitch; %32==4 banks-wise, %4==0 for float4
__global__ __launch_bounds__(256) void attention_kernel(
    const float* __restrict__ qb, const float* __restrict__ kb,
    const float* __restrict__ vb, float* __restrict__ ctx)
{
    const int blk = blockIdx.x;
    const int qblk = blk % (SS / 8);
    const int bh = blk / (SS / 8);
    const int h = bh % HH;
    const int b = bh / HH;
    const int s0 = qblk * 8;
    const int tid = threadIdx.x;

    __shared__ float sc[8][SC_PITCH];
    __shared__ float row_sum[8];

    // ---- phase 1: scores = (q . k) * scale -------------------------------
    {
        const int qi = tid & 7;  // fixed per thread across the idx loop
        const float* qrow = qb + ((size_t)(b * SS + s0 + qi) * DD) + h * HD;
        float4 qreg[16];
#pragma unroll
        for (int j = 0; j < 16; j++) qreg[j] = ((const float4*)qrow)[j];

        for (int idx = tid; idx < 8 * SS; idx += 256) {
            const int kj = idx >> 3;
            const float* krow = kb + ((size_t)(b * SS + kj) * DD) + h * HD;
            float acc = 0.f;
#pragma unroll
            for (int j = 0; j < 16; j++) {
                float4 kv = ((const float4*)krow)[j];
                acc = fmaf(qreg[j].x, kv.x, acc);
                acc = fmaf(qreg[j].y, kv.y, acc);
                acc = fmaf(qreg[j].z, kv.z, acc);
                acc = fmaf(qreg[j].w, kv.w, acc);
            }
            sc[qi][kj] = acc * 0.125f;   // 1/sqrt(64)
        }
    }
    __syncthreads();

    // ---- phase 2: softmax numerators per row (keep sum) ------------------
    {
        const int w = tid >> 6;
        const int lane = tid & 63;
        for (int r = w; r < 8; r += 4) {
            float mx = -1e30f;
            for (int j = lane; j < SS; j += 64) mx = fmaxf(mx, sc[r][j]);
#pragma unroll
            for (int off = 32; off > 0; off >>= 1)
                mx = fmaxf(mx, __shfl_xor(mx, off));
            float sum = 0.f;
            for (int j = lane; j < SS; j += 64) {
                float e = expf(sc[r][j] - mx);
                sc[r][j] = e;
                sum += e;
            }
#pragma unroll
            for (int off = 32; off > 0; off >>= 1)
                sum += __shfl_xor(sum, off);
            if (lane == 0) row_sum[r] = sum;
        }
    }
    __syncthreads();

    // ---- phase 3: ctx = (attn @ v) / sum ---------------------------------
    {
        const int d = tid & 63;
        const int qp = tid >> 6;          // 0..3 ; handles rows qp and qp+4
        float acc0 = 0.f, acc1 = 0.f;
        for (int kj0 = 0; kj0 < SS / 4; kj0++) {
            float4 s0v = *(const float4*)&sc[qp][kj0 * 4];
            float4 s1v = *(const float4*)&sc[qp + 4][kj0 * 4];
            const float* vr = vb + ((size_t)(b * SS + kj0 * 4) * DD) + h * HD + d;
            float v0 = vr[0];
            float v1 = vr[DD];
            float v2 = vr[2 * DD];
            float v3 = vr[3 * DD];
            acc0 = fmaf(s0v.x, v0, acc0);
            acc0 = fmaf(s0v.y, v1, acc0);
            acc0 = fmaf(s0v.z, v2, acc0);
            acc0 = fmaf(s0v.w, v3, acc0);
            acc1 = fmaf(s1v.x, v0, acc1);
            acc1 = fmaf(s1v.y, v1, acc1);
            acc1 = fmaf(s1v.z, v2, acc1);
            acc1 = fmaf(s1v.w, v3, acc1);
        }
        float inv0 = 1.f / row_sum[qp];
        float inv1 = 1.f / row_sum[qp + 4];
        ctx[((size_t)(b * SS + s0 + qp) * DD) + h * HD + d] = acc0 * inv0;
        ctx[((size_t)(b * SS + s0 + qp + 4) * DD) + h * HD + d] = acc1 * inv1;
    }
}

// ---------------------------------------------------------------------------
// x = LayerNorm(x + res) * g + b   (in place on x). One block (128 thr) / row.
// ---------------------------------------------------------------------------
__global__ __launch_bounds__(128) void add_ln_kernel(
    float* __restrict__ x, const float* __restrict__ res,
    const float* __restrict__ g, const float* __restrict__ bta)
{
    const int row = blockIdx.x;
    const int tid = threadIdx.x;
    float* xr = x + (size_t)row * DD;
    const float* rr = res + (size_t)row * DD;

    float4 xv = ((const float4*)xr)[tid];
    float4 rv = ((const float4*)rr)[tid];
    xv.x += rv.x; xv.y += rv.y; xv.z += rv.z; xv.w += rv.w;

    __shared__ float red1[2];
    __shared__ float red2[2];
    const int lane = tid & 63;
    const int w = tid >> 6;

    float s = xv.x + xv.y + xv.z + xv.w;
#pragma unroll
    for (int off = 32; off > 0; off >>= 1) s += __shfl_xor(s, off);
    if (lane == 0) red1[w] = s;
    __syncthreads();
    const float mean = (red1[0] + red1[1]) * (1.f / (float)DD);

    float d0 = xv.x - mean, d1 = xv.y - mean, d2 = xv.z - mean, d3 = xv.w - mean;
    float sq = d0 * d0 + d1 * d1 + d2 * d2 + d3 * d3;
#pragma unroll
    for (int off = 32; off > 0; off >>= 1) sq += __shfl_xor(sq, off);
    if (lane == 0) red2[w] = sq;
    __syncthreads();
    const float inv = 1.f / sqrtf((red2[0] + red2[1]) * (1.f / (float)DD) + 1e-5f);

    float4 gv = ((const float4*)g)[tid];
    float4 bv = ((const float4*)bta)[tid];
    float4 o;
    o.x = d0 * inv * gv.x + bv.x;
    o.y = d1 * inv * gv.y + bv.y;
    o.z = d2 * inv * gv.z + bv.z;
    o.w = d3 * inv * gv.w + bv.w;
    ((float4*)xr)[tid] = o;
}

// ---------------------------------------------------------------------------
// Row softmax over V=32000, in place. One block (256 thr) per row.
// Online (max,sum) pass + normalize pass.
// ---------------------------------------------------------------------------
__global__ __launch_bounds__(256) void softmax_kernel(float* __restrict__ out)
{
    const int row = blockIdx.x;
    float* p = out + (size_t)row * VV;
    const int tid = threadIdx.x;

    float m = -1e30f, s = 0.f;
    for (int j = tid * 4; j < VV; j += 1024) {
        float4 c = *(const float4*)&p[j];
        float lm = fmaxf(fmaxf(c.x, c.y), fmaxf(c.z, c.w));
        if (lm > m) { s *= expf(m - lm); m = lm; }
        s += expf(c.x - m) + expf(c.y - m) + expf(c.z - m) + expf(c.w - m);
    }
#pragma unroll
    for (int off = 32; off > 0; off >>= 1) {
        float mo = __shfl_xor(m, off);
        float so = __shfl_xor(s, off);
        float nm = fmaxf(m, mo);
        s = s * expf(m - nm) + so * expf(mo - nm);
        m = nm;
    }
    __shared__ float ms[4], ss2[4];
    const int lane = tid & 63;
    const int w = tid >> 6;
    if (lane == 0) { ms[w] = m; ss2[w] = s; }
    __syncthreads();
    float fm = fmaxf(fmaxf(ms[0], ms[1]), fmaxf(ms[2], ms[3]));
    float fs = ss2[0] * expf(ms[0] - fm) + ss2[1] * expf(ms[1] - fm) +
               ss2[2] * expf(ms[2] - fm) + ss2[3] * expf(ms[3] - fm);
    const float inv = 1.f / fs;
    for (int j = tid * 4; j < VV; j += 1024) {
        float4 c = *(const float4*)&p[j];
        c.x = expf(c.x - fm) * inv;
        c.y = expf(c.y - fm) * inv;
        c.z = expf(c.z - fm) * inv;
        c.w = expf(c.w - fm) * inv;
        *(float4*)&p[j] = c;
    }
}

// ---------------------------------------------------------------------------
static inline void launch_gemm(const float* A, const float* W, const float* bias,
                               float* C, int M, int N, int K, int relu,
                               hipStream_t st)
{
    dim3 grid(N / 64, (M + 127) / 128);
    gemm_bias_kernel<<<grid, 256, 0, st>>>(A, W, bias, C, M, N, K, relu);
}

extern "C" void kernel_launch(void* const* d_in, const int* in_sizes, int n_in,
                              void* d_out, int out_size, void* d_ws, size_t ws_size,
                              hipStream_t stream)
{
    const int*   tokens = (const int*)  d_in[0];
    const float* emb    = (const float*)d_in[1];
    const float* wq     = (const float*)d_in[2];
    const float* bq     = (const float*)d_in[3];
    const float* wk     = (const float*)d_in[4];
    const float* bk     = (const float*)d_in[5];
    const float* wv     = (const float*)d_in[6];
    const float* bv     = (const float*)d_in[7];
    const float* wo     = (const float*)d_in[8];
    const float* bo     = (const float*)d_in[9];
    const float* ln1g   = (const float*)d_in[10];
    const float* ln1b   = (const float*)d_in[11];
    const float* w1     = (const float*)d_in[12];
    const float* b1     = (const float*)d_in[13];
    const float* w2     = (const float*)d_in[14];
    const float* b2     = (const float*)d_in[15];
    const float* ln2g   = (const float*)d_in[16];
    const float* ln2b   = (const float*)d_in[17];
    const float* fcw    = (const float*)d_in[18];
    const float* fcb    = (const float*)d_in[19];
    float* out = (float*)d_out;

    const size_t XN = (size_t)MM * DD;        // 2,048,000
    float* x    = (float*)d_ws;
    float* q    = x   + XN;
    float* k    = q   + XN;
    float* v    = k   + XN;
    float* ctx  = v   + XN;
    float* attn = ctx + XN;
    // FFN hidden (4000 x 2048 = 32 MB) parked in tail of d_out (dead before
    // the final GEMM writes logits).
    float* hbuf = out + ((size_t)MM * VV - (size_t)MM * FFD);

    embed_pe_kernel<<<(MM * DD) / 256, 256, 0, stream>>>(tokens, emb, x);

    for (int l = 0; l < LL; l++) {
        const size_t wo2 = (size_t)l * DD * DD;
        launch_gemm(x, wq + wo2, bq + l * DD, q, MM, DD, DD, 0, stream);
        launch_gemm(x, wk + wo2, bk + l * DD, k, MM, DD, DD, 0, stream);
        launch_gemm(x, wv + wo2, bv + l * DD, v, MM, DD, DD, 0, stream);
        attention_kernel<<<BB * HH * (SS / 8), 256, 0, stream>>>(q, k, v, ctx);
        launch_gemm(ctx, wo + wo2, bo + l * DD, attn, MM, DD, DD, 0, stream);
        add_ln_kernel<<<MM, 128, 0, stream>>>(x, attn, ln1g + l * DD, ln1b + l * DD);
        launch_gemm(x, w1 + (size_t)l * DD * FFD, b1 + l * FFD, hbuf, MM, FFD, DD, 1, stream);
        launch_gemm(hbuf, w2 + (size_t)l * FFD * DD, b2 + l * DD, attn, MM, DD, FFD, 0, stream);
        add_ln_kernel<<<MM, 128, 0, stream>>>(x, attn, ln2g + l * DD, ln2b + l * DD);
    }

    launch_gemm(x, fcw, fcb, out, MM, VV, DD, 0, stream);
    softmax_kernel<<<MM, 256, 0, stream>>>(out);
}